// Round 5
// baseline (98.305 us; speedup 1.0000x reference)
//
#include <hip/hip_runtime.h>

typedef int i32x4 __attribute__((ext_vector_type(4)));

#define QMAXF 127.0f

// ---------------------------------------------------------------------------
// Weight quantization: one block per output row (cout).  ~2 us.
// ws[row] = max(|w[row,:]*s|)/127 ; qw[row,k] = rint(w[row,k]*s / ws[row])
// ---------------------------------------------------------------------------
__global__ __launch_bounds__(256) void quant_w_kernel(
    const float* __restrict__ w, const float* __restrict__ act_scale,
    signed char* __restrict__ qw, float* __restrict__ wscale)
{
    const int row = blockIdx.x;
    const int t   = threadIdx.x;
    const float s = act_scale[0];

    float4 v = *reinterpret_cast<const float4*>(w + (size_t)row * 1024 + t * 4);
    float a0 = v.x * s, a1 = v.y * s, a2 = v.z * s, a3 = v.w * s;
    float m = fmaxf(fmaxf(fabsf(a0), fabsf(a1)), fmaxf(fabsf(a2), fabsf(a3)));

    #pragma unroll
    for (int i = 1; i < 64; i <<= 1)
        m = fmaxf(m, __shfl_xor(m, i));

    __shared__ float wmax[4];
    if ((t & 63) == 0) wmax[t >> 6] = m;
    __syncthreads();
    m = fmaxf(fmaxf(wmax[0], wmax[1]), fmaxf(wmax[2], wmax[3]));

    const float wsc = m / QMAXF;

    int q0 = (int)rintf(a0 / wsc);
    int q1 = (int)rintf(a1 / wsc);
    int q2 = (int)rintf(a2 / wsc);
    int q3 = (int)rintf(a3 / wsc);
    int packed = (q0 & 255) | ((q1 & 255) << 8) | ((q2 & 255) << 16) | ((q3 & 255) << 24);
    reinterpret_cast<int*>(qw)[row * 256 + t] = packed;

    if (t == 0) wscale[row] = wsc;
}

// ---------------------------------------------------------------------------
// Fused quant(x) + int8 GEMM + dequant epilogue.
//
// Block: BM=64 rows x full N=1024.  8 waves; wave w owns 64 x 128 (n-strip).
// K-tiles of 64.  Per kt:
//   stage(kt+1): B 64KB via global_load_lds (qw, L2-resident),
//                A 16KB f32 from x -> regs (HBM stream)
//   compute(kt): ds_read frags -> 32x mfma_i32_16x16x64_i8 per wave
//   drain, quantize A-regs -> ds_write int8 into buf^1, barrier
// x is read once, quantized once (bit-exact rintf/clip), no xq intermediate.
//
// LDS stride 64B; conflict-free swizzle: slot ^= (row>>1)&3  (8-lane groups
// cover all 32 banks).  Applied on the pre-swizzled GLOBAL source for B
// (gload_lds dest linear) and directly on the ds_write address for A.
// ---------------------------------------------------------------------------
#define BM 64
#define NKT 16   // K / 64

__global__ __launch_bounds__(512, 2) void gemm_fused_kernel(
    const float* __restrict__ x, const signed char* __restrict__ qw,
    const float* __restrict__ act_scale,
    const float* __restrict__ wscale, const float* __restrict__ bias,
    float* __restrict__ out)
{
    const int K = 1024, N = 1024;
    __shared__ __align__(16) signed char As[2][BM * 64];    //  8 KB
    __shared__ __align__(16) signed char Bs[2][1024 * 64];  // 128 KB

    const int t    = threadIdx.x;
    const int lane = t & 63;
    const int w    = t >> 6;      // wave 0..7 -> n-strip w*128
    const int lrow = lane & 15;
    const int ks   = lane >> 4;   // 16B K-slot 0..3

    const int m0 = blockIdx.x * BM;
    const float s = act_scale[0];

    // A staging geometry: thread t handles row t>>3, 8 consecutive f32.
    const int arow = t >> 3;
    const int ac8  = t & 7;           // 8-float chunk index within row

    i32x4 acc[4][8] = {};             // [m-frag][n-frag] = 128 VGPRs
    float4 a0, a1;                    // in-flight A f32 (next tile)

    auto STAGE_B = [&](int kt, int buf) {
        #pragma unroll
        for (int j = 0; j < 8; ++j) {
            const int idx  = j * 512 + t;        // 16B unit, 0..4095
            const int row  = idx >> 2;           // 0..1023
            const int slot = idx & 3;
            const int gs   = slot ^ ((row >> 1) & 3);
            const signed char* src = qw + (size_t)row * K + kt * 64 + gs * 16;
            __builtin_amdgcn_global_load_lds(
                (const __attribute__((address_space(1))) void*)src,
                (__attribute__((address_space(3))) void*)(&Bs[buf][0] + idx * 16),
                16, 0, 0);
        }
    };
    auto LOAD_A = [&](int kt) {
        const float* p = x + (size_t)(m0 + arow) * K + kt * 64 + ac8 * 8;
        a0 = *reinterpret_cast<const float4*>(p);
        a1 = *reinterpret_cast<const float4*>(p + 4);
    };
    auto QUANT_A = [&](int buf) {
        int q0 = (int)rintf(fminf(fmaxf(a0.x / s, -QMAXF), QMAXF));
        int q1 = (int)rintf(fminf(fmaxf(a0.y / s, -QMAXF), QMAXF));
        int q2 = (int)rintf(fminf(fmaxf(a0.z / s, -QMAXF), QMAXF));
        int q3 = (int)rintf(fminf(fmaxf(a0.w / s, -QMAXF), QMAXF));
        int q4 = (int)rintf(fminf(fmaxf(a1.x / s, -QMAXF), QMAXF));
        int q5 = (int)rintf(fminf(fmaxf(a1.y / s, -QMAXF), QMAXF));
        int q6 = (int)rintf(fminf(fmaxf(a1.z / s, -QMAXF), QMAXF));
        int q7 = (int)rintf(fminf(fmaxf(a1.w / s, -QMAXF), QMAXF));
        int p0 = (q0 & 255) | ((q1 & 255) << 8) | ((q2 & 255) << 16) | ((q3 & 255) << 24);
        int p1 = (q4 & 255) | ((q5 & 255) << 8) | ((q6 & 255) << 16) | ((q7 & 255) << 24);
        const int slot  = ac8 >> 1;
        const int sslot = slot ^ ((arow >> 1) & 3);
        const int boff  = arow * 64 + sslot * 16 + (ac8 & 1) * 8;
        *reinterpret_cast<int2*>(&As[buf][0] + boff) = make_int2(p0, p1);
    };

    // ---- prologue: stage tile 0 ----
    STAGE_B(0, 0);
    LOAD_A(0);
    QUANT_A(0);            // compiler waits vmcnt for a0/a1
    __syncthreads();       // drains vmcnt(0) (B lds landed) + lgkm + barrier

    #pragma unroll 2
    for (int kt = 0; kt < NKT; ++kt) {
        const int cur = kt & 1;
        const bool more = (kt + 1 < NKT);
        if (more) {
            STAGE_B(kt + 1, cur ^ 1);
            LOAD_A(kt + 1);
        }

        // ds_read fragments of current tile
        i32x4 Af[4], Bf[8];
        #pragma unroll
        for (int mf = 0; mf < 4; ++mf) {
            const int row  = mf * 16 + lrow;
            const int slot = ks ^ ((row >> 1) & 3);
            Af[mf] = *reinterpret_cast<const i32x4*>(&As[cur][0] + row * 64 + slot * 16);
        }
        #pragma unroll
        for (int nf = 0; nf < 8; ++nf) {
            const int row  = w * 128 + nf * 16 + lrow;
            const int slot = ks ^ ((row >> 1) & 3);
            Bf[nf] = *reinterpret_cast<const i32x4*>(&Bs[cur][0] + row * 64 + slot * 16);
        }

        __builtin_amdgcn_s_setprio(1);
        #pragma unroll
        for (int mf = 0; mf < 4; ++mf)
            #pragma unroll
            for (int nf = 0; nf < 8; ++nf)
                acc[mf][nf] = __builtin_amdgcn_mfma_i32_16x16x64_i8(
                    Af[mf], Bf[nf], acc[mf][nf], 0, 0, 0);
        __builtin_amdgcn_s_setprio(0);

        if (more) QUANT_A(cur ^ 1);   // waits its own vmcnt; writes buf^1
        __syncthreads();              // full drain + barrier -> next tile ready
    }

    // ---- epilogue: dequant + bias ----
    float wsv[8], bv[8];
    int   gnc[8];
    #pragma unroll
    for (int nf = 0; nf < 8; ++nf) {
        const int gn = w * 128 + nf * 16 + lrow;
        gnc[nf] = gn;
        wsv[nf] = wscale[gn];
        bv[nf]  = bias[gn];
    }
    #pragma unroll
    for (int mf = 0; mf < 4; ++mf) {
        #pragma unroll
        for (int r = 0; r < 4; ++r) {
            const int gm = m0 + mf * 16 + ks * 4 + r;
            float* orow = out + (size_t)gm * N;
            #pragma unroll
            for (int nf = 0; nf < 8; ++nf)
                orow[gnc[nf]] = (float)acc[mf][nf][r] * wsv[nf] + bv[nf];
        }
    }
}

// ---------------------------------------------------------------------------
extern "C" void kernel_launch(void* const* d_in, const int* in_sizes, int n_in,
                              void* d_out, int out_size, void* d_ws, size_t ws_size,
                              hipStream_t stream)
{
    const float* x         = (const float*)d_in[0];
    const float* weight    = (const float*)d_in[1];
    const float* bias      = (const float*)d_in[2];
    const float* act_scale = (const float*)d_in[3];
    float* out             = (float*)d_out;

    const int K = 1024;
    const int N = 1024;
    const int M = in_sizes[0] / K;   // 32768

    // workspace: qw (N*K int8) | wscale (N f32)
    char* wsb = (char*)d_ws;
    signed char* qw  = (signed char*)wsb;
    float*       wsc = (float*)(wsb + (size_t)N * K);

    quant_w_kernel<<<N, 256, 0, stream>>>(weight, act_scale, qw, wsc);
    gemm_fused_kernel<<<M / BM, 512, 0, stream>>>(x, qw, act_scale, wsc, bias, out);
}